// Round 7
// baseline (580.899 us; speedup 1.0000x reference)
//
#include <hip/hip_runtime.h>

// FastGuidedFilter: 24 planes (8x3) of 1024x1024 f32, r=8 (17x17 clipped box).
//
// Two barrier-free full-row sweep kernels through d_ws (A,b planes, 201 MB).
// Wave = full 1024-col row (16 aligned cols/lane), sweeps CH=16 output rows.
// Vertical 17-tap window = per-lane running sums (lead add / trail subtract,
// validity folded as 0/1 scale, rows clamped so loads are unconditional).
// Horizontal 17-tap window applied ONLY at the 16 output steps:
//   K1: prefix/suffix + one shfl(+-1) exchange per quantity (win17_nbr)
//   K2: per-lane 32-col-span running sums, window = local 15-step slide
// Column-edge counts are compile-time constants (only lanes 0/63 clipped).
// No LDS arrays, no barriers.
//
// Fallback: if ws_size < 201 MB, run the round-1 fused single kernel.

#define HH 1024
#define WW 1024
#define NPLANES 24
#define RAD 8
#define CH 16
#define NCHROW (HH / CH)                 // 64 row-chunks per plane
#define NCHUNKS (NPLANES * NCHROW)       // 1536 single-wave blocks

// per-column horizontal count reciprocal: interior = 1/17; lane0/lane63 edges
// are compile-time constants per m.
__device__ __forceinline__ float invCCf(int lane, int m /*compile-time*/) {
    const float cL = (m < 8) ? (1.f / (float)(m + 9)) : (1.f / 17.f);
    const float cR = (m > 7) ? (1.f / (float)(24 - m)) : (1.f / 17.f);
    float v = 1.f / 17.f;
    v = (lane == 0)  ? cL : v;
    v = (lane == 63) ? cR : v;
    return v;
}

// Load the lane's 16 aligned cols of one (valid, clamped) row.
__device__ __forceinline__ void load16(const float* __restrict__ rowp, int lane,
                                       float* __restrict__ d) {
    const float4* p = (const float4*)rowp + lane * 4;
#pragma unroll
    for (int k = 0; k < 4; ++k) {
        float4 a = p[k];
        d[4 * k + 0] = a.x; d[4 * k + 1] = a.y;
        d[4 * k + 2] = a.z; d[4 * k + 3] = a.w;
    }
}

// Load 32 cols [16*lane-8, 16*lane+24); OOB cols -> 0.
__device__ __forceinline__ void load32(const float* __restrict__ rowp, int lane,
                                       float* __restrict__ d) {
    const int c0 = lane * 16 - 8;
#pragma unroll
    for (int k = 0; k < 8; ++k) {
        int c = c0 + 4 * k;
        float4 a = make_float4(0.f, 0.f, 0.f, 0.f);
        if ((unsigned)c < (unsigned)WW) a = *(const float4*)(rowp + c);
        d[4 * k + 0] = a.x; d[4 * k + 1] = a.y;
        d[4 * k + 2] = a.z; d[4 * k + 3] = a.w;
    }
}

// 17-tap zero-padded horizontal window of s[] (lane owns cols 16l..16l+15).
__device__ __forceinline__ void win17_nbr(const float* __restrict__ s, int lane,
                                          float* __restrict__ w) {
    float P[16];
    P[0] = s[0];
#pragma unroll
    for (int m = 1; m < 16; ++m) P[m] = P[m - 1] + s[m];
    float S[8];                       // S[k] = sum s[8+k .. 15]
    S[7] = s[15];
#pragma unroll
    for (int k = 6; k >= 0; --k) S[k] = S[k + 1] + s[8 + k];
    float SL[8], PR[8];
#pragma unroll
    for (int k = 0; k < 8; ++k) SL[k] = __shfl_up(S[k], 1, 64);
#pragma unroll
    for (int k = 0; k < 8; ++k) PR[k] = __shfl_down(P[k], 1, 64);
    const bool hasL = (lane > 0), hasR = (lane < 63);
#pragma unroll
    for (int m = 0; m < 8; ++m) w[m] = (hasL ? SL[m] : 0.f) + P[m + 8];
    w[8] = P[15] + (hasR ? PR[0] : 0.f);
#pragma unroll
    for (int m = 9; m < 16; ++m) w[m] = (P[15] - P[m - 9]) + (hasR ? PR[m - 8] : 0.f);
}

__global__ __launch_bounds__(64)
void fgf_ab(const float* __restrict__ x, const float* __restrict__ y,
            float* __restrict__ Aw, float* __restrict__ bw)
{
    const int lane  = threadIdx.x;
    const int chunk = blockIdx.x;
    const int p  = chunk / NCHROW;
    const int R0 = (chunk - p * NCHROW) * CH;
    const size_t po = (size_t)p * HH * WW;
    const float* xp = x + po;
    const float* yp = y + po;
    float* Ap = Aw + po;
    float* bp = bw + po;

    float vsx[16], vsy[16], vsxy[16], vsxx[16];
#pragma unroll
    for (int m = 0; m < 16; ++m) { vsx[m] = vsy[m] = vsxy[m] = vsxx[m] = 0.f; }

    // warmup: rows R0-8 .. R0+7 (top-clamped; validity as 0/1 scale)
#pragma unroll
    for (int s = 0; s < 2 * RAD; ++s) {
        const int r = R0 - RAD + s;
        const float sc = (r >= 0) ? 1.f : 0.f;
        const int rs = (r >= 0) ? r : 0;
        float xl[16], yl[16];
        load16(xp + (size_t)rs * WW, lane, xl);
        load16(yp + (size_t)rs * WW, lane, yl);
#pragma unroll
        for (int m = 0; m < 16; ++m) {
            float tx = sc * xl[m], ty = sc * yl[m];
            vsx[m] += tx; vsy[m] += ty;
            vsxy[m] = fmaf(tx, yl[m], vsxy[m]);
            vsxx[m] = fmaf(tx, xl[m], vsxx[m]);
        }
    }

#pragma unroll
    for (int t = 0; t < CH; ++t) {
        const int i = R0 + t;
        // lead row i+8 (bottom-clamped)
        {
            const int rl = i + RAD;
            const float sl = (rl < HH) ? 1.f : 0.f;
            const int rls = (rl < HH) ? rl : (HH - 1);
            float xl[16], yl[16];
            load16(xp + (size_t)rls * WW, lane, xl);
            load16(yp + (size_t)rls * WW, lane, yl);
#pragma unroll
            for (int m = 0; m < 16; ++m) {
                float tx = sl * xl[m], ty = sl * yl[m];
                vsx[m] += tx; vsy[m] += ty;
                vsxy[m] = fmaf(tx, yl[m], vsxy[m]);
                vsxx[m] = fmaf(tx, xl[m], vsxx[m]);
            }
        }
        // trail row i-9 (only once it entered the sum; top-clamped)
        if (t > 0) {
            const int rt = i - RAD - 1;
            const float st = (rt >= 0) ? 1.f : 0.f;
            const int rts = (rt >= 0) ? rt : 0;
            float xt[16], yt[16];
            load16(xp + (size_t)rts * WW, lane, xt);
            load16(yp + (size_t)rts * WW, lane, yt);
#pragma unroll
            for (int m = 0; m < 16; ++m) {
                float tx = st * xt[m], ty = st * yt[m];
                vsx[m] -= tx; vsy[m] -= ty;
                vsxy[m] = fmaf(-tx, yt[m], vsxy[m]);
                vsxx[m] = fmaf(-tx, xt[m], vsxx[m]);
            }
        }

        // output row i: horizontal windows + A,b (staged to cap live regs)
        const float invCR = 1.f / (float)(min(i + RAD, HH - 1) - max(i - RAD, 0) + 1);
        float w[16], mx[16], my[16], cov[16];
        win17_nbr(vsx, lane, w);
#pragma unroll
        for (int m = 0; m < 16; ++m) mx[m] = w[m] * (invCR * invCCf(lane, m));
        win17_nbr(vsy, lane, w);
#pragma unroll
        for (int m = 0; m < 16; ++m) my[m] = w[m] * (invCR * invCCf(lane, m));
        win17_nbr(vsxy, lane, w);
#pragma unroll
        for (int m = 0; m < 16; ++m) cov[m] = w[m] * (invCR * invCCf(lane, m)) - mx[m] * my[m];
        win17_nbr(vsxx, lane, w);
#pragma unroll
        for (int m = 0; m < 16; ++m) {
            float vr = w[m] * (invCR * invCCf(lane, m)) - mx[m] * mx[m];
            float A  = cov[m] / (vr + 1e-8f);
            cov[m] = A;                        // cov -> A
            my[m]  = my[m] - A * mx[m];        // my  -> b
        }
        float4* Ar = (float4*)(Ap + (size_t)i * WW) + lane * 4;
        float4* Br = (float4*)(bp + (size_t)i * WW) + lane * 4;
#pragma unroll
        for (int k = 0; k < 4; ++k) {
            Ar[k] = make_float4(cov[4*k+0], cov[4*k+1], cov[4*k+2], cov[4*k+3]);
            Br[k] = make_float4(my[4*k+0],  my[4*k+1],  my[4*k+2],  my[4*k+3]);
        }
    }
}

__global__ __launch_bounds__(64)
void fgf_out(const float* __restrict__ Aw, const float* __restrict__ bw,
             const float* __restrict__ x, float* __restrict__ out)
{
    const int lane  = threadIdx.x;
    const int chunk = blockIdx.x;
    const int p  = chunk / NCHROW;
    const int R0 = (chunk - p * NCHROW) * CH;
    const size_t po = (size_t)p * HH * WW;
    const float* Apl = Aw + po;
    const float* bpl = bw + po;
    const float* xp  = x + po;
    float* op = out + po;

    // vertical running sums over the lane's 32-col span [16l-8, 16l+24)
    float vsA[32], vsB[32];
#pragma unroll
    for (int m = 0; m < 32; ++m) { vsA[m] = vsB[m] = 0.f; }

#pragma unroll
    for (int s = 0; s < 2 * RAD; ++s) {
        const int r = R0 - RAD + s;
        const float sc = (r >= 0) ? 1.f : 0.f;
        const int rs = (r >= 0) ? r : 0;
        float al[32], bl[32];
        load32(Apl + (size_t)rs * WW, lane, al);
        load32(bpl + (size_t)rs * WW, lane, bl);
#pragma unroll
        for (int m = 0; m < 32; ++m) {
            vsA[m] = fmaf(sc, al[m], vsA[m]);
            vsB[m] = fmaf(sc, bl[m], vsB[m]);
        }
    }

#pragma unroll
    for (int t = 0; t < CH; ++t) {
        const int i = R0 + t;
        {
            const int rl = i + RAD;
            const float sl = (rl < HH) ? 1.f : 0.f;
            const int rls = (rl < HH) ? rl : (HH - 1);
            float al[32], bl[32];
            load32(Apl + (size_t)rls * WW, lane, al);
            load32(bpl + (size_t)rls * WW, lane, bl);
#pragma unroll
            for (int m = 0; m < 32; ++m) {
                vsA[m] = fmaf(sl, al[m], vsA[m]);
                vsB[m] = fmaf(sl, bl[m], vsB[m]);
            }
        }
        if (t > 0) {
            const int rt = i - RAD - 1;
            const float st = (rt >= 0) ? 1.f : 0.f;
            const int rts = (rt >= 0) ? rt : 0;
            float at[32], bt[32];
            load32(Apl + (size_t)rts * WW, lane, at);
            load32(bpl + (size_t)rts * WW, lane, bt);
#pragma unroll
            for (int m = 0; m < 32; ++m) {
                vsA[m] = fmaf(-st, at[m], vsA[m]);
                vsB[m] = fmaf(-st, bt[m], vsB[m]);
            }
        }

        // horizontal window = local 17-tap slide over the 32-span
        const float invCR = 1.f / (float)(min(i + RAD, HH - 1) - max(i - RAD, 0) + 1);
        float wA[16], wB[16];
        {
            float a = vsA[0], b = vsB[0];
#pragma unroll
            for (int k = 1; k < 17; ++k) { a += vsA[k]; b += vsB[k]; }
            wA[0] = a; wB[0] = b;
#pragma unroll
            for (int m = 1; m < 16; ++m) {
                a += vsA[m + 16] - vsA[m - 1];
                b += vsB[m + 16] - vsB[m - 1];
                wA[m] = a; wB[m] = b;
            }
        }
        float xv[16];
        load16(xp + (size_t)i * WW, lane, xv);
        float4* Orow = (float4*)(op + (size_t)i * WW) + lane * 4;
#pragma unroll
        for (int k = 0; k < 4; ++k) {
            float4 o;
#pragma unroll
            for (int e = 0; e < 4; ++e) {
                const int m = 4 * k + e;
                float invN = invCR * invCCf(lane, m);
                float val = fmaf(wA[m] * invN, xv[m], wB[m] * invN);
                ((float*)&o)[e] = val;
            }
            Orow[k] = o;
        }
    }
}

// ---------------- fallback: round-1 fused kernel (if ws too small) ----------------
#define TH 32
#define TW 64
#define RAWROWS (TH + 32)
#define RAWCOLS (TW + 32)
#define RAWSTR  (RAWCOLS + 1)
#define HROWS RAWROWS
#define HCOLS (TW + 16)
#define FHSTR  (HCOLS + 1)
#define BROWS (TH + 16)
#define STR2  (TW + 1)
#define REGA 15552
#define REGB 20736
#define SMEM_FLOATS (REGA + REGB)
#define SMEM_BYTES  (SMEM_FLOATS * 4)

extern "C" __global__ __launch_bounds__(256)
void fgf_fused(const float* __restrict__ x, const float* __restrict__ y,
               float* __restrict__ out)
{
    extern __shared__ float smem[];
    float* RA = smem;
    float* RB = smem + REGA;

    const int tid = threadIdx.x;
    const int tc = blockIdx.x;
    const int tr = blockIdx.y;
    const int p  = blockIdx.z;
    const int R0 = tr * TH;
    const int C0 = tc * TW;
    const size_t planeOff = (size_t)p * HH * WW;
    const float* xp = x + planeOff;
    const float* yp = y + planeOff;
    float* op = out + planeOff;

    float* rawx = RA;
    float* rawy = RA + RAWROWS * RAWSTR;

    for (int idx = tid; idx < RAWROWS * RAWCOLS; idx += 256) {
        int rr = idx / RAWCOLS;
        int cc = idx - rr * RAWCOLS;
        int gi = R0 - 16 + rr;
        int gj = C0 - 16 + cc;
        float vx = 0.f, vy = 0.f;
        if (gi >= 0 && gi < HH && gj >= 0 && gj < WW) {
            size_t g = (size_t)gi * WW + gj;
            vx = xp[g]; vy = yp[g];
        }
        rawx[rr * RAWSTR + cc] = vx;
        rawy[rr * RAWSTR + cc] = vy;
    }
    __syncthreads();

    {
        const int q   = tid >> 6;
        const int row = tid & 63;
        const float* rx = rawx + row * RAWSTR;
        const float* ry = rawy + row * RAWSTR;
        float* hq = RB + (q * HROWS + row) * FHSTR;
#define H1_SCAN(VAL_EXPR)                                    \
        {                                                    \
            float s = 0.f;                                   \
            for (int k = 0; k < 16; ++k) { int c = k; s += (VAL_EXPR); } \
            for (int j = 0; j < HCOLS; ++j) {                \
                { int c = j + 16; s += (VAL_EXPR); }         \
                hq[j] = s;                                   \
                { int c = j; s -= (VAL_EXPR); }              \
            }                                                \
        }
        if (q == 0)      H1_SCAN(rx[c])
        else if (q == 1) H1_SCAN(ry[c])
        else if (q == 2) H1_SCAN(rx[c] * ry[c])
        else             H1_SCAN(rx[c] * rx[c])
#undef H1_SCAN
    }
    __syncthreads();

    for (int item = tid; item < 4 * HCOLS; item += 256) {
        int q   = item / HCOLS;
        int col = item - q * HCOLS;
        const float* hq = RB + q * HROWS * FHSTR + col;
        float* bq = RA + q * BROWS * FHSTR + col;
        float s = 0.f;
        for (int k = 0; k < 16; ++k) s += hq[k * FHSTR];
        for (int i = 0; i < BROWS; ++i) {
            s += hq[(i + 16) * FHSTR];
            bq[i * FHSTR] = s;
            s -= hq[i * FHSTR];
        }
    }
    __syncthreads();

    for (int it = tid; it < BROWS * HCOLS; it += 256) {
        int ii = it / HCOLS;
        int jj = it - ii * HCOLS;
        int gi = R0 - 8 + ii;
        int gj = C0 - 8 + jj;
        float Av = 0.f, bv = 0.f;
        if (gi >= 0 && gi < HH && gj >= 0 && gj < WW) {
            float cntR = (float)(min(gi + RAD, HH - 1) - max(gi - RAD, 0) + 1);
            float cntC = (float)(min(gj + RAD, WW - 1) - max(gj - RAD, 0) + 1);
            float invN = 1.f / (cntR * cntC);
            float sxv  = RA[0 * BROWS * FHSTR + ii * FHSTR + jj];
            float syv  = RA[1 * BROWS * FHSTR + ii * FHSTR + jj];
            float sxyv = RA[2 * BROWS * FHSTR + ii * FHSTR + jj];
            float sxxv = RA[3 * BROWS * FHSTR + ii * FHSTR + jj];
            float mx  = sxv * invN;
            float my  = syv * invN;
            float cv  = sxyv * invN - mx * my;
            float vr  = sxxv * invN - mx * mx;
            Av = cv / (vr + 1e-8f);
            bv = my - Av * mx;
        }
        RB[ii * FHSTR + jj] = Av;
        RB[BROWS * FHSTR + ii * FHSTR + jj] = bv;
    }
    __syncthreads();

    if (tid < 2 * BROWS) {
        int q   = tid / BROWS;
        int row = tid - q * BROWS;
        const float* src = RB + q * BROWS * FHSTR + row * FHSTR;
        float* dst = RA + (q * BROWS + row) * STR2;
        float s = 0.f;
        for (int k = 0; k < 16; ++k) s += src[k];
        for (int j = 0; j < TW; ++j) {
            s += src[j + 16];
            dst[j] = s;
            s -= src[j];
        }
    }
    __syncthreads();

    if (tid < 2 * TW) {
        int q   = tid >> 6;
        int col = tid & 63;
        const float* src = RA + q * BROWS * STR2 + col;
        float* dst = RB + q * TH * STR2 + col;
        float s = 0.f;
        for (int k = 0; k < 16; ++k) s += src[k * STR2];
        for (int i = 0; i < TH; ++i) {
            s += src[(i + 16) * STR2];
            dst[i * STR2] = s;
            s -= src[i * STR2];
        }
    }
    __syncthreads();

    for (int it = tid; it < TH * TW; it += 256) {
        int ii = it >> 6;
        int jj = it & 63;
        int gi = R0 + ii;
        int gj = C0 + jj;
        float cntR = (float)(min(gi + RAD, HH - 1) - max(gi - RAD, 0) + 1);
        float cntC = (float)(min(gj + RAD, WW - 1) - max(gj - RAD, 0) + 1);
        float invN = 1.f / (cntR * cntC);
        float mA = RB[ii * STR2 + jj] * invN;
        float mb = RB[TH * STR2 + ii * STR2 + jj] * invN;
        size_t g = (size_t)gi * WW + gj;
        op[g] = mA * xp[g] + mb;
    }
}

extern "C" void kernel_launch(void* const* d_in, const int* in_sizes, int n_in,
                              void* d_out, int out_size, void* d_ws, size_t ws_size,
                              hipStream_t stream) {
    const float* x = (const float*)d_in[0];
    const float* y = (const float*)d_in[1];
    float* out = (float*)d_out;

    const size_t planeFloats = (size_t)NPLANES * HH * WW;   // 24M
    const size_t wsNeed = 2 * planeFloats * sizeof(float);  // 201.3 MB

    if (ws_size >= wsNeed) {
        float* Aw = (float*)d_ws;
        float* bw = Aw + planeFloats;
        fgf_ab<<<dim3(NCHUNKS), 64, 0, stream>>>(x, y, Aw, bw);
        fgf_out<<<dim3(NCHUNKS), 64, 0, stream>>>(Aw, bw, x, out);
    } else {
        hipFuncSetAttribute((const void*)fgf_fused,
                            hipFuncAttributeMaxDynamicSharedMemorySize, SMEM_BYTES);
        dim3 grid(WW / TW, HH / TH, NPLANES);
        fgf_fused<<<grid, 256, SMEM_BYTES, stream>>>(x, y, out);
    }
}

// Round 8
// 427.027 us; speedup vs baseline: 1.3603x; 1.3603x over previous
//
#include <hip/hip_runtime.h>

// FastGuidedFilter: 24 planes (8x3) of 1024x1024 f32, r=8 (17x17 clipped box).
//
// Two barrier-free full-row sweep kernels through d_ws (A,b planes, 201 MB).
// Round-4 kernel bodies (best measured: 190+87 us) with one structural fix:
// 4 independent chunk-waves packed per 256-thread workgroup. 64-thread
// workgroups capped residency at ~5 waves/CU (occ 16%); 256-thread blocks
// reach 11+ waves/CU (round-2 evidence), overlapping K1's VALU chains.
//
// Per wave: full 1024-col row (16 cols/lane), sweeps CH=8 output rows.
// Horizontal 17-tap windows per lane from its 32-col span [16l-8,16l+24)
// (8 float4 loads; halo overlap is L1-resident), two 15-add prefix chains.
// Vertical 17-tap window via running sums of windowed rows; trailing row
// (r-17) re-loaded (L2/L3-warm) and re-windowed. No LDS, no shuffles,
// no barriers.
//
// Fallback: if ws_size < 201 MB, run the round-1 fused single kernel.

#define HH 1024
#define WW 1024
#define NPLANES 24
#define RAD 8
#define CH 8
#define NCHROW (HH / CH)                 // 128 row-chunks per plane
#define NCHUNKS (NPLANES * NCHROW)       // 3072 chunk-waves
#define WPB 4                            // chunk-waves per 256-thread block
#define NBLK (NCHUNKS / WPB)             // 768 blocks

// Load 32 cols [16*lane-8, 16*lane+24) of one row; OOB cols -> 0.
__device__ __forceinline__ void load32(const float* __restrict__ rowp, int lane,
                                       float* __restrict__ d) {
    const int c0 = lane * 16 - 8;
#pragma unroll
    for (int k = 0; k < 8; ++k) {
        int c = c0 + 4 * k;
        float4 a = make_float4(0.f, 0.f, 0.f, 0.f);
        if ((unsigned)c < (unsigned)WW) a = *(const float4*)(rowp + c);
        d[4 * k + 0] = a.x; d[4 * k + 1] = a.y;
        d[4 * k + 2] = a.z; d[4 * k + 3] = a.w;
    }
}

// acc[m] += SIGN * sum(v[m .. m+16])   (17-tap window, local indices)
template <int SIGN>
__device__ __forceinline__ void accum_hwin(const float* __restrict__ v,
                                           float* __restrict__ acc) {
    float L[16], R[16];
    L[0] = v[0];
#pragma unroll
    for (int m = 1; m < 16; ++m) L[m] = L[m - 1] + v[m];
    R[0] = v[16];
#pragma unroll
    for (int m = 1; m < 16; ++m) R[m] = R[m - 1] + v[16 + m];
    const float L15 = L[15];
#pragma unroll
    for (int m = 0; m < 16; ++m) {
        float w = (m ? (L15 - L[m - 1]) : L15) + R[m];
        acc[m] += (SIGN > 0) ? w : -w;
    }
}

// acc[m] += SIGN * sum(a[k]*b[k], k=m..m+16)  (product folded via FMA)
template <int SIGN>
__device__ __forceinline__ void accum_hwin_prod(const float* __restrict__ a,
                                                const float* __restrict__ b,
                                                float* __restrict__ acc) {
    float L[16], R[16];
    L[0] = a[0] * b[0];
#pragma unroll
    for (int m = 1; m < 16; ++m) L[m] = __builtin_fmaf(a[m], b[m], L[m - 1]);
    R[0] = a[16] * b[16];
#pragma unroll
    for (int m = 1; m < 16; ++m) R[m] = __builtin_fmaf(a[16 + m], b[16 + m], R[m - 1]);
    const float L15 = L[15];
#pragma unroll
    for (int m = 0; m < 16; ++m) {
        float w = (m ? (L15 - L[m - 1]) : L15) + R[m];
        acc[m] += (SIGN > 0) ? w : -w;
    }
}

__global__ __launch_bounds__(256)
void fgf_ab(const float* __restrict__ x, const float* __restrict__ y,
            float* __restrict__ Aw, float* __restrict__ bw)
{
    const int lane  = threadIdx.x & 63;
    const int chunk = blockIdx.x * WPB + (threadIdx.x >> 6);
    const int p     = chunk / NCHROW;
    const int R0    = (chunk - p * NCHROW) * CH;
    const size_t po = (size_t)p * HH * WW;
    const float* xp = x + po;
    const float* yp = y + po;
    float* Ap = Aw + po;
    float* bp = bw + po;

    float invCC[16];
#pragma unroll
    for (int m = 0; m < 16; ++m) {
        int j = lane * 16 + m;
        int c = min(j + RAD, WW - 1) - max(j - RAD, 0) + 1;
        invCC[m] = 1.f / (float)c;
    }

    float sx[16], sy[16], sxy[16], sxx[16];
#pragma unroll
    for (int m = 0; m < 16; ++m) { sx[m] = 0.f; sy[m] = 0.f; sxy[m] = 0.f; sxx[m] = 0.f; }

    float xv[32], yv[32];

    for (int r = R0 - RAD; r <= R0 + CH - 1 + RAD; ++r) {
        if ((unsigned)r < (unsigned)HH) {
            load32(xp + (size_t)r * WW, lane, xv);
            load32(yp + (size_t)r * WW, lane, yv);
            accum_hwin<+1>(xv, sx);
            accum_hwin<+1>(yv, sy);
            accum_hwin_prod<+1>(xv, yv, sxy);
            accum_hwin_prod<+1>(xv, xv, sxx);
        }
        const int rt = r - (2 * RAD + 1);
        if (rt >= R0 - RAD && rt >= 0) {
            load32(xp + (size_t)rt * WW, lane, xv);
            load32(yp + (size_t)rt * WW, lane, yv);
            accum_hwin<-1>(xv, sx);
            accum_hwin<-1>(yv, sy);
            accum_hwin_prod<-1>(xv, yv, sxy);
            accum_hwin_prod<-1>(xv, xv, sxx);
        }

        const int i = r - RAD;
        if (i >= R0) {
            float cR = (float)(min(i + RAD, HH - 1) - max(i - RAD, 0) + 1);
            float invCR = 1.f / cR;
            float Ao[16], Bo[16];
#pragma unroll
            for (int m = 0; m < 16; ++m) {
                float invN = invCR * invCC[m];
                float mx = sx[m] * invN, my = sy[m] * invN;
                float cov = sxy[m] * invN - mx * my;
                float vr  = sxx[m] * invN - mx * mx;
                float A = cov / (vr + 1e-8f);
                Ao[m] = A;
                Bo[m] = my - A * mx;
            }
            float4* Arow = (float4*)(Ap + (size_t)i * WW);
            float4* Brow = (float4*)(bp + (size_t)i * WW);
#pragma unroll
            for (int k = 0; k < 4; ++k) {
                Arow[lane * 4 + k] = make_float4(Ao[k*4+0], Ao[k*4+1], Ao[k*4+2], Ao[k*4+3]);
                Brow[lane * 4 + k] = make_float4(Bo[k*4+0], Bo[k*4+1], Bo[k*4+2], Bo[k*4+3]);
            }
        }
    }
}

__global__ __launch_bounds__(256)
void fgf_out(const float* __restrict__ Aw, const float* __restrict__ bw,
             const float* __restrict__ x, float* __restrict__ out)
{
    const int lane  = threadIdx.x & 63;
    const int chunk = blockIdx.x * WPB + (threadIdx.x >> 6);
    const int p     = chunk / NCHROW;
    const int R0    = (chunk - p * NCHROW) * CH;
    const size_t po = (size_t)p * HH * WW;
    const float* Apl = Aw + po;
    const float* bpl = bw + po;
    const float* xp  = x + po;
    float* op = out + po;

    float invCC[16];
#pragma unroll
    for (int m = 0; m < 16; ++m) {
        int j = lane * 16 + m;
        int c = min(j + RAD, WW - 1) - max(j - RAD, 0) + 1;
        invCC[m] = 1.f / (float)c;
    }

    float sA[16], sB[16];
#pragma unroll
    for (int m = 0; m < 16; ++m) { sA[m] = 0.f; sB[m] = 0.f; }

    float v[32];

    for (int r = R0 - RAD; r <= R0 + CH - 1 + RAD; ++r) {
        if ((unsigned)r < (unsigned)HH) {
            load32(Apl + (size_t)r * WW, lane, v);
            accum_hwin<+1>(v, sA);
            load32(bpl + (size_t)r * WW, lane, v);
            accum_hwin<+1>(v, sB);
        }
        const int rt = r - (2 * RAD + 1);
        if (rt >= R0 - RAD && rt >= 0) {
            load32(Apl + (size_t)rt * WW, lane, v);
            accum_hwin<-1>(v, sA);
            load32(bpl + (size_t)rt * WW, lane, v);
            accum_hwin<-1>(v, sB);
        }

        const int i = r - RAD;
        if (i >= R0) {
            float cR = (float)(min(i + RAD, HH - 1) - max(i - RAD, 0) + 1);
            float invCR = 1.f / cR;
            const float4* xrow = (const float4*)(xp + (size_t)i * WW);
            float4* Orow = (float4*)(op + (size_t)i * WW);
#pragma unroll
            for (int k = 0; k < 4; ++k) {
                float4 xv4 = xrow[lane * 4 + k];
                float4 o;
                float invN0 = invCR * invCC[k*4+0];
                float invN1 = invCR * invCC[k*4+1];
                float invN2 = invCR * invCC[k*4+2];
                float invN3 = invCR * invCC[k*4+3];
                o.x = (sA[k*4+0] * invN0) * xv4.x + sB[k*4+0] * invN0;
                o.y = (sA[k*4+1] * invN1) * xv4.y + sB[k*4+1] * invN1;
                o.z = (sA[k*4+2] * invN2) * xv4.z + sB[k*4+2] * invN2;
                o.w = (sA[k*4+3] * invN3) * xv4.w + sB[k*4+3] * invN3;
                Orow[lane * 4 + k] = o;
            }
        }
    }
}

// ---------------- fallback: round-1 fused kernel (if ws too small) ----------------
#define TH 32
#define TW 64
#define RAWROWS (TH + 32)
#define RAWCOLS (TW + 32)
#define RAWSTR  (RAWCOLS + 1)
#define HROWS RAWROWS
#define HCOLS (TW + 16)
#define FHSTR  (HCOLS + 1)
#define BROWS (TH + 16)
#define STR2  (TW + 1)
#define REGA 15552
#define REGB 20736
#define SMEM_FLOATS (REGA + REGB)
#define SMEM_BYTES  (SMEM_FLOATS * 4)

extern "C" __global__ __launch_bounds__(256)
void fgf_fused(const float* __restrict__ x, const float* __restrict__ y,
               float* __restrict__ out)
{
    extern __shared__ float smem[];
    float* RA = smem;
    float* RB = smem + REGA;

    const int tid = threadIdx.x;
    const int tc = blockIdx.x;
    const int tr = blockIdx.y;
    const int p  = blockIdx.z;
    const int R0 = tr * TH;
    const int C0 = tc * TW;
    const size_t planeOff = (size_t)p * HH * WW;
    const float* xp = x + planeOff;
    const float* yp = y + planeOff;
    float* op = out + planeOff;

    float* rawx = RA;
    float* rawy = RA + RAWROWS * RAWSTR;

    for (int idx = tid; idx < RAWROWS * RAWCOLS; idx += 256) {
        int rr = idx / RAWCOLS;
        int cc = idx - rr * RAWCOLS;
        int gi = R0 - 16 + rr;
        int gj = C0 - 16 + cc;
        float vx = 0.f, vy = 0.f;
        if (gi >= 0 && gi < HH && gj >= 0 && gj < WW) {
            size_t g = (size_t)gi * WW + gj;
            vx = xp[g]; vy = yp[g];
        }
        rawx[rr * RAWSTR + cc] = vx;
        rawy[rr * RAWSTR + cc] = vy;
    }
    __syncthreads();

    {
        const int q   = tid >> 6;
        const int row = tid & 63;
        const float* rx = rawx + row * RAWSTR;
        const float* ry = rawy + row * RAWSTR;
        float* hq = RB + (q * HROWS + row) * FHSTR;
#define H1_SCAN(VAL_EXPR)                                    \
        {                                                    \
            float s = 0.f;                                   \
            for (int k = 0; k < 16; ++k) { int c = k; s += (VAL_EXPR); } \
            for (int j = 0; j < HCOLS; ++j) {                \
                { int c = j + 16; s += (VAL_EXPR); }         \
                hq[j] = s;                                   \
                { int c = j; s -= (VAL_EXPR); }              \
            }                                                \
        }
        if (q == 0)      H1_SCAN(rx[c])
        else if (q == 1) H1_SCAN(ry[c])
        else if (q == 2) H1_SCAN(rx[c] * ry[c])
        else             H1_SCAN(rx[c] * rx[c])
#undef H1_SCAN
    }
    __syncthreads();

    for (int item = tid; item < 4 * HCOLS; item += 256) {
        int q   = item / HCOLS;
        int col = item - q * HCOLS;
        const float* hq = RB + q * HROWS * FHSTR + col;
        float* bq = RA + q * BROWS * FHSTR + col;
        float s = 0.f;
        for (int k = 0; k < 16; ++k) s += hq[k * FHSTR];
        for (int i = 0; i < BROWS; ++i) {
            s += hq[(i + 16) * FHSTR];
            bq[i * FHSTR] = s;
            s -= hq[i * FHSTR];
        }
    }
    __syncthreads();

    for (int it = tid; it < BROWS * HCOLS; it += 256) {
        int ii = it / HCOLS;
        int jj = it - ii * HCOLS;
        int gi = R0 - 8 + ii;
        int gj = C0 - 8 + jj;
        float Av = 0.f, bv = 0.f;
        if (gi >= 0 && gi < HH && gj >= 0 && gj < WW) {
            float cntR = (float)(min(gi + RAD, HH - 1) - max(gi - RAD, 0) + 1);
            float cntC = (float)(min(gj + RAD, WW - 1) - max(gj - RAD, 0) + 1);
            float invN = 1.f / (cntR * cntC);
            float sxv  = RA[0 * BROWS * FHSTR + ii * FHSTR + jj];
            float syv  = RA[1 * BROWS * FHSTR + ii * FHSTR + jj];
            float sxyv = RA[2 * BROWS * FHSTR + ii * FHSTR + jj];
            float sxxv = RA[3 * BROWS * FHSTR + ii * FHSTR + jj];
            float mx  = sxv * invN;
            float my  = syv * invN;
            float cv  = sxyv * invN - mx * my;
            float vr  = sxxv * invN - mx * mx;
            Av = cv / (vr + 1e-8f);
            bv = my - Av * mx;
        }
        RB[ii * FHSTR + jj] = Av;
        RB[BROWS * FHSTR + ii * FHSTR + jj] = bv;
    }
    __syncthreads();

    if (tid < 2 * BROWS) {
        int q   = tid / BROWS;
        int row = tid - q * BROWS;
        const float* src = RB + q * BROWS * FHSTR + row * FHSTR;
        float* dst = RA + (q * BROWS + row) * STR2;
        float s = 0.f;
        for (int k = 0; k < 16; ++k) s += src[k];
        for (int j = 0; j < TW; ++j) {
            s += src[j + 16];
            dst[j] = s;
            s -= src[j];
        }
    }
    __syncthreads();

    if (tid < 2 * TW) {
        int q   = tid >> 6;
        int col = tid & 63;
        const float* src = RA + q * BROWS * STR2 + col;
        float* dst = RB + q * TH * STR2 + col;
        float s = 0.f;
        for (int k = 0; k < 16; ++k) s += src[k * STR2];
        for (int i = 0; i < TH; ++i) {
            s += src[(i + 16) * STR2];
            dst[i * STR2] = s;
            s -= src[i * STR2];
        }
    }
    __syncthreads();

    for (int it = tid; it < TH * TW; it += 256) {
        int ii = it >> 6;
        int jj = it & 63;
        int gi = R0 + ii;
        int gj = C0 + jj;
        float cntR = (float)(min(gi + RAD, HH - 1) - max(gi - RAD, 0) + 1);
        float cntC = (float)(min(gj + RAD, WW - 1) - max(gj - RAD, 0) + 1);
        float invN = 1.f / (cntR * cntC);
        float mA = RB[ii * STR2 + jj] * invN;
        float mb = RB[TH * STR2 + ii * STR2 + jj] * invN;
        size_t g = (size_t)gi * WW + gj;
        op[g] = mA * xp[g] + mb;
    }
}

extern "C" void kernel_launch(void* const* d_in, const int* in_sizes, int n_in,
                              void* d_out, int out_size, void* d_ws, size_t ws_size,
                              hipStream_t stream) {
    const float* x = (const float*)d_in[0];
    const float* y = (const float*)d_in[1];
    float* out = (float*)d_out;

    const size_t planeFloats = (size_t)NPLANES * HH * WW;   // 24M
    const size_t wsNeed = 2 * planeFloats * sizeof(float);  // 201.3 MB

    if (ws_size >= wsNeed) {
        float* Aw = (float*)d_ws;
        float* bw = Aw + planeFloats;
        fgf_ab<<<dim3(NBLK), 256, 0, stream>>>(x, y, Aw, bw);
        fgf_out<<<dim3(NBLK), 256, 0, stream>>>(Aw, bw, x, out);
    } else {
        hipFuncSetAttribute((const void*)fgf_fused,
                            hipFuncAttributeMaxDynamicSharedMemorySize, SMEM_BYTES);
        dim3 grid(WW / TW, HH / TH, NPLANES);
        fgf_fused<<<grid, 256, SMEM_BYTES, stream>>>(x, y, out);
    }
}

// Round 9
// 299.767 us; speedup vs baseline: 1.9378x; 1.4245x over previous
//
#include <hip/hip_runtime.h>

// FastGuidedFilter: 24 planes (8x3) of 1024x1024 f32, r=8 (17x17 clipped box).
//
// Two barrier-free full-row sweep kernels through d_ws (A,b planes, 201 MB).
// 64-thread blocks (1 wave), wave = full 1024-col row (16 aligned cols/lane),
// CH=8 output rows per wave, 3072 waves per kernel.
//
// Structure (vertical-sums-first; halves loads AND windowing vs round 4):
//  - per input row: load16 (exactly one 4KB row, no halo redundancy) and
//    elementwise-update per-lane vertical running sums (lead add/trail sub,
//    validity folded as 0/1 scale, rows clamped so loads are unconditional).
//  - per OUTPUT row only: 17-tap horizontal window via win17_nbr
//    (per-lane prefix/suffix + 16 independent shfl(+-1); zero-padded edges)
//    then A,b (K1) or final fma (K2).
// Column-edge counts are compile-time selects (only lanes 0/63 clipped).
// No LDS arrays, no barriers.
//
// Fallback: if ws_size < 201 MB, run the round-1 fused single kernel.

#define HH 1024
#define WW 1024
#define NPLANES 24
#define RAD 8
#define CH 8
#define NCHROW (HH / CH)                 // 128 row-chunks per plane
#define NCHUNKS (NPLANES * NCHROW)       // 3072 single-wave blocks

// per-column horizontal count reciprocal: interior = 1/17; only lanes 0/63
// have clipped columns; m is compile-time.
__device__ __forceinline__ float invCCf(int lane, int m) {
    const float cL = (m < 8) ? (1.f / (float)(m + 9)) : (1.f / 17.f);
    const float cR = (m > 7) ? (1.f / (float)(24 - m)) : (1.f / 17.f);
    float v = 1.f / 17.f;
    v = (lane == 0)  ? cL : v;
    v = (lane == 63) ? cR : v;
    return v;
}

// Load the lane's 16 aligned cols of one (valid, clamped) row.
__device__ __forceinline__ void load16(const float* __restrict__ rowp, int lane,
                                       float* __restrict__ d) {
    const float4* p = (const float4*)rowp + lane * 4;
#pragma unroll
    for (int k = 0; k < 4; ++k) {
        float4 a = p[k];
        d[4 * k + 0] = a.x; d[4 * k + 1] = a.y;
        d[4 * k + 2] = a.z; d[4 * k + 3] = a.w;
    }
}

// 17-tap zero-padded horizontal window of s[] (lane owns cols 16l..16l+15).
// w[m] = sum s over cols [j-8, j+8] ∩ [0,1024), j = 16*lane+m.
__device__ __forceinline__ void win17_nbr(const float* __restrict__ s, int lane,
                                          float* __restrict__ w) {
    float P[16];
    P[0] = s[0];
#pragma unroll
    for (int m = 1; m < 16; ++m) P[m] = P[m - 1] + s[m];
    float S[8];                       // S[k] = sum s[8+k .. 15]
    S[7] = s[15];
#pragma unroll
    for (int k = 6; k >= 0; --k) S[k] = S[k + 1] + s[8 + k];
    float SL[8], PR[8];
#pragma unroll
    for (int k = 0; k < 8; ++k) SL[k] = __shfl_up(S[k], 1, 64);
#pragma unroll
    for (int k = 0; k < 8; ++k) PR[k] = __shfl_down(P[k], 1, 64);
    const bool hasL = (lane > 0), hasR = (lane < 63);
#pragma unroll
    for (int m = 0; m < 8; ++m) w[m] = (hasL ? SL[m] : 0.f) + P[m + 8];
    w[8] = P[15] + (hasR ? PR[0] : 0.f);
#pragma unroll
    for (int m = 9; m < 16; ++m) w[m] = (P[15] - P[m - 9]) + (hasR ? PR[m - 8] : 0.f);
}

__global__ __launch_bounds__(64)
void fgf_ab(const float* __restrict__ x, const float* __restrict__ y,
            float* __restrict__ Aw, float* __restrict__ bw)
{
    const int lane  = threadIdx.x;
    const int chunk = blockIdx.x;
    const int p  = chunk / NCHROW;
    const int R0 = (chunk - p * NCHROW) * CH;
    const size_t po = (size_t)p * HH * WW;
    const float* xp = x + po;
    const float* yp = y + po;
    float* Ap = Aw + po;
    float* bp = bw + po;

    float vsx[16], vsy[16], vsxy[16], vsxx[16];
#pragma unroll
    for (int m = 0; m < 16; ++m) { vsx[m] = vsy[m] = vsxy[m] = vsxx[m] = 0.f; }

    // warmup: rows R0-8 .. R0+7 (top-clamped; validity as 0/1 scale)
#pragma unroll 1
    for (int s = 0; s < 2 * RAD; ++s) {
        const int r = R0 - RAD + s;
        const float sc = (r >= 0) ? 1.f : 0.f;
        const int rs = (r >= 0) ? r : 0;
        float xl[16], yl[16];
        load16(xp + (size_t)rs * WW, lane, xl);
        load16(yp + (size_t)rs * WW, lane, yl);
#pragma unroll
        for (int m = 0; m < 16; ++m) {
            float tx = sc * xl[m], ty = sc * yl[m];
            vsx[m] += tx; vsy[m] += ty;
            vsxy[m] = fmaf(tx, yl[m], vsxy[m]);
            vsxx[m] = fmaf(tx, xl[m], vsxx[m]);
        }
    }

    for (int t = 0; t < CH; ++t) {
        const int i = R0 + t;
        // lead row i+8 (bottom-clamped)
        {
            const int rl = i + RAD;
            const float sl = (rl < HH) ? 1.f : 0.f;
            const int rls = (rl < HH) ? rl : (HH - 1);
            float xl[16], yl[16];
            load16(xp + (size_t)rls * WW, lane, xl);
            load16(yp + (size_t)rls * WW, lane, yl);
#pragma unroll
            for (int m = 0; m < 16; ++m) {
                float tx = sl * xl[m], ty = sl * yl[m];
                vsx[m] += tx; vsy[m] += ty;
                vsxy[m] = fmaf(tx, yl[m], vsxy[m]);
                vsxx[m] = fmaf(tx, xl[m], vsxx[m]);
            }
        }
        // trail row i-9 (top-clamped; scaled 0 if it never entered)
        if (t > 0) {
            const int rt = i - RAD - 1;
            const float st = (rt >= 0) ? 1.f : 0.f;
            const int rts = (rt >= 0) ? rt : 0;
            float xt[16], yt[16];
            load16(xp + (size_t)rts * WW, lane, xt);
            load16(yp + (size_t)rts * WW, lane, yt);
#pragma unroll
            for (int m = 0; m < 16; ++m) {
                float tx = st * xt[m], ty = st * yt[m];
                vsx[m] -= tx; vsy[m] -= ty;
                vsxy[m] = fmaf(-tx, yt[m], vsxy[m]);
                vsxx[m] = fmaf(-tx, xt[m], vsxx[m]);
            }
        }

        // output row i: 4 horizontal windows + A,b (staged, buffers reused)
        const float invCR = 1.f / (float)(min(i + RAD, HH - 1) - max(i - RAD, 0) + 1);
        float w[16], mxv[16], myv[16], covv[16];
        win17_nbr(vsx, lane, w);
#pragma unroll
        for (int m = 0; m < 16; ++m) mxv[m] = w[m] * (invCR * invCCf(lane, m));
        win17_nbr(vsy, lane, w);
#pragma unroll
        for (int m = 0; m < 16; ++m) myv[m] = w[m] * (invCR * invCCf(lane, m));
        win17_nbr(vsxy, lane, w);
#pragma unroll
        for (int m = 0; m < 16; ++m)
            covv[m] = w[m] * (invCR * invCCf(lane, m)) - mxv[m] * myv[m];
        win17_nbr(vsxx, lane, w);
#pragma unroll
        for (int m = 0; m < 16; ++m) {
            float vr = w[m] * (invCR * invCCf(lane, m)) - mxv[m] * mxv[m];
            float A  = covv[m] / (vr + 1e-8f);
            covv[m] = A;                        // covv -> A
            myv[m]  = myv[m] - A * mxv[m];      // myv  -> b
        }
        float4* Ar = (float4*)(Ap + (size_t)i * WW) + lane * 4;
        float4* Br = (float4*)(bp + (size_t)i * WW) + lane * 4;
#pragma unroll
        for (int k = 0; k < 4; ++k) {
            Ar[k] = make_float4(covv[4*k+0], covv[4*k+1], covv[4*k+2], covv[4*k+3]);
            Br[k] = make_float4(myv[4*k+0],  myv[4*k+1],  myv[4*k+2],  myv[4*k+3]);
        }
    }
}

__global__ __launch_bounds__(64)
void fgf_out(const float* __restrict__ Aw, const float* __restrict__ bw,
             const float* __restrict__ x, float* __restrict__ out)
{
    const int lane  = threadIdx.x;
    const int chunk = blockIdx.x;
    const int p  = chunk / NCHROW;
    const int R0 = (chunk - p * NCHROW) * CH;
    const size_t po = (size_t)p * HH * WW;
    const float* Apl = Aw + po;
    const float* bpl = bw + po;
    const float* xp  = x + po;
    float* op = out + po;

    float vsA[16], vsB[16];
#pragma unroll
    for (int m = 0; m < 16; ++m) { vsA[m] = vsB[m] = 0.f; }

#pragma unroll 1
    for (int s = 0; s < 2 * RAD; ++s) {
        const int r = R0 - RAD + s;
        const float sc = (r >= 0) ? 1.f : 0.f;
        const int rs = (r >= 0) ? r : 0;
        float al[16], bl[16];
        load16(Apl + (size_t)rs * WW, lane, al);
        load16(bpl + (size_t)rs * WW, lane, bl);
#pragma unroll
        for (int m = 0; m < 16; ++m) {
            vsA[m] = fmaf(sc, al[m], vsA[m]);
            vsB[m] = fmaf(sc, bl[m], vsB[m]);
        }
    }

    for (int t = 0; t < CH; ++t) {
        const int i = R0 + t;
        {
            const int rl = i + RAD;
            const float sl = (rl < HH) ? 1.f : 0.f;
            const int rls = (rl < HH) ? rl : (HH - 1);
            float al[16], bl[16];
            load16(Apl + (size_t)rls * WW, lane, al);
            load16(bpl + (size_t)rls * WW, lane, bl);
#pragma unroll
            for (int m = 0; m < 16; ++m) {
                vsA[m] = fmaf(sl, al[m], vsA[m]);
                vsB[m] = fmaf(sl, bl[m], vsB[m]);
            }
        }
        if (t > 0) {
            const int rt = i - RAD - 1;
            const float st = (rt >= 0) ? 1.f : 0.f;
            const int rts = (rt >= 0) ? rt : 0;
            float at[16], bt[16];
            load16(Apl + (size_t)rts * WW, lane, at);
            load16(bpl + (size_t)rts * WW, lane, bt);
#pragma unroll
            for (int m = 0; m < 16; ++m) {
                vsA[m] = fmaf(-st, at[m], vsA[m]);
                vsB[m] = fmaf(-st, bt[m], vsB[m]);
            }
        }

        const float invCR = 1.f / (float)(min(i + RAD, HH - 1) - max(i - RAD, 0) + 1);
        float wA[16], wB[16], xv[16];
        win17_nbr(vsA, lane, wA);
        win17_nbr(vsB, lane, wB);
        load16(xp + (size_t)i * WW, lane, xv);
        float4* Orow = (float4*)(op + (size_t)i * WW) + lane * 4;
#pragma unroll
        for (int k = 0; k < 4; ++k) {
            float4 o;
#pragma unroll
            for (int e = 0; e < 4; ++e) {
                const int m = 4 * k + e;
                float invN = invCR * invCCf(lane, m);
                ((float*)&o)[e] = fmaf(wA[m] * invN, xv[m], wB[m] * invN);
            }
            Orow[k] = o;
        }
    }
}

// ---------------- fallback: round-1 fused kernel (if ws too small) ----------------
#define TH 32
#define TW 64
#define RAWROWS (TH + 32)
#define RAWCOLS (TW + 32)
#define RAWSTR  (RAWCOLS + 1)
#define HROWS RAWROWS
#define HCOLS (TW + 16)
#define FHSTR  (HCOLS + 1)
#define BROWS (TH + 16)
#define STR2  (TW + 1)
#define REGA 15552
#define REGB 20736
#define SMEM_FLOATS (REGA + REGB)
#define SMEM_BYTES  (SMEM_FLOATS * 4)

extern "C" __global__ __launch_bounds__(256)
void fgf_fused(const float* __restrict__ x, const float* __restrict__ y,
               float* __restrict__ out)
{
    extern __shared__ float smem[];
    float* RA = smem;
    float* RB = smem + REGA;

    const int tid = threadIdx.x;
    const int tc = blockIdx.x;
    const int tr = blockIdx.y;
    const int p  = blockIdx.z;
    const int R0 = tr * TH;
    const int C0 = tc * TW;
    const size_t planeOff = (size_t)p * HH * WW;
    const float* xp = x + planeOff;
    const float* yp = y + planeOff;
    float* op = out + planeOff;

    float* rawx = RA;
    float* rawy = RA + RAWROWS * RAWSTR;

    for (int idx = tid; idx < RAWROWS * RAWCOLS; idx += 256) {
        int rr = idx / RAWCOLS;
        int cc = idx - rr * RAWCOLS;
        int gi = R0 - 16 + rr;
        int gj = C0 - 16 + cc;
        float vx = 0.f, vy = 0.f;
        if (gi >= 0 && gi < HH && gj >= 0 && gj < WW) {
            size_t g = (size_t)gi * WW + gj;
            vx = xp[g]; vy = yp[g];
        }
        rawx[rr * RAWSTR + cc] = vx;
        rawy[rr * RAWSTR + cc] = vy;
    }
    __syncthreads();

    {
        const int q   = tid >> 6;
        const int row = tid & 63;
        const float* rx = rawx + row * RAWSTR;
        const float* ry = rawy + row * RAWSTR;
        float* hq = RB + (q * HROWS + row) * FHSTR;
#define H1_SCAN(VAL_EXPR)                                    \
        {                                                    \
            float s = 0.f;                                   \
            for (int k = 0; k < 16; ++k) { int c = k; s += (VAL_EXPR); } \
            for (int j = 0; j < HCOLS; ++j) {                \
                { int c = j + 16; s += (VAL_EXPR); }         \
                hq[j] = s;                                   \
                { int c = j; s -= (VAL_EXPR); }              \
            }                                                \
        }
        if (q == 0)      H1_SCAN(rx[c])
        else if (q == 1) H1_SCAN(ry[c])
        else if (q == 2) H1_SCAN(rx[c] * ry[c])
        else             H1_SCAN(rx[c] * rx[c])
#undef H1_SCAN
    }
    __syncthreads();

    for (int item = tid; item < 4 * HCOLS; item += 256) {
        int q   = item / HCOLS;
        int col = item - q * HCOLS;
        const float* hq = RB + q * HROWS * FHSTR + col;
        float* bq = RA + q * BROWS * FHSTR + col;
        float s = 0.f;
        for (int k = 0; k < 16; ++k) s += hq[k * FHSTR];
        for (int i = 0; i < BROWS; ++i) {
            s += hq[(i + 16) * FHSTR];
            bq[i * FHSTR] = s;
            s -= hq[i * FHSTR];
        }
    }
    __syncthreads();

    for (int it = tid; it < BROWS * HCOLS; it += 256) {
        int ii = it / HCOLS;
        int jj = it - ii * HCOLS;
        int gi = R0 - 8 + ii;
        int gj = C0 - 8 + jj;
        float Av = 0.f, bv = 0.f;
        if (gi >= 0 && gi < HH && gj >= 0 && gj < WW) {
            float cntR = (float)(min(gi + RAD, HH - 1) - max(gi - RAD, 0) + 1);
            float cntC = (float)(min(gj + RAD, WW - 1) - max(gj - RAD, 0) + 1);
            float invN = 1.f / (cntR * cntC);
            float sxv  = RA[0 * BROWS * FHSTR + ii * FHSTR + jj];
            float syv  = RA[1 * BROWS * FHSTR + ii * FHSTR + jj];
            float sxyv = RA[2 * BROWS * FHSTR + ii * FHSTR + jj];
            float sxxv = RA[3 * BROWS * FHSTR + ii * FHSTR + jj];
            float mx  = sxv * invN;
            float my  = syv * invN;
            float cv  = sxyv * invN - mx * my;
            float vr  = sxxv * invN - mx * mx;
            Av = cv / (vr + 1e-8f);
            bv = my - Av * mx;
        }
        RB[ii * FHSTR + jj] = Av;
        RB[BROWS * FHSTR + ii * FHSTR + jj] = bv;
    }
    __syncthreads();

    if (tid < 2 * BROWS) {
        int q   = tid / BROWS;
        int row = tid - q * BROWS;
        const float* src = RB + q * BROWS * FHSTR + row * FHSTR;
        float* dst = RA + (q * BROWS + row) * STR2;
        float s = 0.f;
        for (int k = 0; k < 16; ++k) s += src[k];
        for (int j = 0; j < TW; ++j) {
            s += src[j + 16];
            dst[j] = s;
            s -= src[j];
        }
    }
    __syncthreads();

    if (tid < 2 * TW) {
        int q   = tid >> 6;
        int col = tid & 63;
        const float* src = RA + q * BROWS * STR2 + col;
        float* dst = RB + q * TH * STR2 + col;
        float s = 0.f;
        for (int k = 0; k < 16; ++k) s += src[k * STR2];
        for (int i = 0; i < TH; ++i) {
            s += src[(i + 16) * STR2];
            dst[i * STR2] = s;
            s -= src[i * STR2];
        }
    }
    __syncthreads();

    for (int it = tid; it < TH * TW; it += 256) {
        int ii = it >> 6;
        int jj = it & 63;
        int gi = R0 + ii;
        int gj = C0 + jj;
        float cntR = (float)(min(gi + RAD, HH - 1) - max(gi - RAD, 0) + 1);
        float cntC = (float)(min(gj + RAD, WW - 1) - max(gj - RAD, 0) + 1);
        float invN = 1.f / (cntR * cntC);
        float mA = RB[ii * STR2 + jj] * invN;
        float mb = RB[TH * STR2 + ii * STR2 + jj] * invN;
        size_t g = (size_t)gi * WW + gj;
        op[g] = mA * xp[g] + mb;
    }
}

extern "C" void kernel_launch(void* const* d_in, const int* in_sizes, int n_in,
                              void* d_out, int out_size, void* d_ws, size_t ws_size,
                              hipStream_t stream) {
    const float* x = (const float*)d_in[0];
    const float* y = (const float*)d_in[1];
    float* out = (float*)d_out;

    const size_t planeFloats = (size_t)NPLANES * HH * WW;   // 24M
    const size_t wsNeed = 2 * planeFloats * sizeof(float);  // 201.3 MB

    if (ws_size >= wsNeed) {
        float* Aw = (float*)d_ws;
        float* bw = Aw + planeFloats;
        fgf_ab<<<dim3(NCHUNKS), 64, 0, stream>>>(x, y, Aw, bw);
        fgf_out<<<dim3(NCHUNKS), 64, 0, stream>>>(Aw, bw, x, out);
    } else {
        hipFuncSetAttribute((const void*)fgf_fused,
                            hipFuncAttributeMaxDynamicSharedMemorySize, SMEM_BYTES);
        dim3 grid(WW / TW, HH / TH, NPLANES);
        fgf_fused<<<grid, 256, SMEM_BYTES, stream>>>(x, y, out);
    }
}